// Round 2
// baseline (751.344 us; speedup 1.0000x reference)
//
#include <hip/hip_runtime.h>
#include <cstdint>
#include <cstddef>

// Problem constants (B=8, N=256, H=128, IN_DIM=259)
#define B_ 8
#define N_ 256
#define H_ 128

typedef float f32x4 __attribute__((ext_vector_type(4)));
typedef float f32x16 __attribute__((ext_vector_type(16)));
typedef int i32x4 __attribute__((ext_vector_type(4)));
typedef int i32x2 __attribute__((ext_vector_type(2)));
typedef __bf16 bf16x8 __attribute__((ext_vector_type(8)));
typedef unsigned int u32;
typedef unsigned short u16;

// ---------- helpers ----------
__device__ __forceinline__ u32 pack_bf16_pair(float lo, float hi) {
  u16 a = __builtin_bit_cast(u16, (__bf16)lo);
  u16 b = __builtin_bit_cast(u16, (__bf16)hi);
  return (u32)a | ((u32)b << 16);
}

__device__ __forceinline__ float silu_f(float x) {
  // x * sigmoid(x) = x / (1 + exp(-x))
  return x * __builtin_amdgcn_rcpf(1.0f + __expf(-x));
}

__device__ __forceinline__ f32x16 mfma_bf16(i32x4 a, i32x4 b, f32x16 c) {
  return __builtin_amdgcn_mfma_f32_32x32x16_bf16(
      __builtin_bit_cast(bf16x8, a), __builtin_bit_cast(bf16x8, b), c, 0, 0, 0);
}

// ---------- precompute: R[b,n,g] = x[b,n]·W1[:, :128]ᵀ ;
//                        U[b,n,g] = x[b,n]·W1[:,128:256]ᵀ + b1 + W1[:,256:259]·bd ----------
__global__ void prep_ru_kernel(const float* __restrict__ x_emb,
                               const float* __restrict__ W1,
                               const float* __restrict__ b1,
                               const float* __restrict__ bd,
                               float* __restrict__ R,
                               float* __restrict__ U) {
  __shared__ float xs[16][H_];
  const int t = threadIdx.x;          // 0..127 (= output channel g)
  const int row0 = blockIdx.x * 16;   // rows over flattened (b*N+n)
#pragma unroll
  for (int r = 0; r < 16; ++r)
    xs[r][t] = x_emb[(size_t)(row0 + r) * H_ + t];
  __syncthreads();

  const float* w1g = W1 + (size_t)t * 259;
  float accR[16], accU[16];
#pragma unroll
  for (int r = 0; r < 16; ++r) { accR[r] = 0.f; accU[r] = 0.f; }
  for (int h = 0; h < H_; ++h) {
    float wa = w1g[h];
    float wb = w1g[128 + h];
#pragma unroll
    for (int r = 0; r < 16; ++r) {
      accR[r] += xs[r][h] * wa;
      accU[r] += xs[r][h] * wb;
    }
  }
  float bias = b1[t] + bd[0] * w1g[256] + bd[1] * w1g[257] + bd[2] * w1g[258];
#pragma unroll
  for (int r = 0; r < 16; ++r) {
    R[(size_t)(row0 + r) * H_ + t] = accR[r];
    U[(size_t)(row0 + r) * H_ + t] = accU[r] + bias;
  }
}

// ---------- precompute: We = W1[:,256:259]·Wd (fold edge decoder into layer-1) as bf16;
//                        W2 cast to bf16 ----------
__global__ void prep_w_kernel(const float* __restrict__ W1,
                              const float* __restrict__ Wd,
                              const float* __restrict__ W2,
                              u16* __restrict__ We_b,
                              u16* __restrict__ W2_b) {
  const int idx = blockIdx.x * 256 + threadIdx.x;  // 0..16383
  const int g = idx >> 7, h = idx & 127;
  const float* w1g = W1 + (size_t)g * 259 + 256;
  float we = w1g[0] * Wd[h] + w1g[1] * Wd[128 + h] + w1g[2] * Wd[256 + h];
  We_b[idx] = __builtin_bit_cast(u16, (__bf16)we);
  W2_b[idx] = __builtin_bit_cast(u16, (__bf16)W2[idx]);
}

// ---------- main fused kernel ----------
// Wave = one (b,i). 32x32x16 bf16 MFMA: M=channel(128: 4 m-tiles), N=32 tokens(j), K=128.
// Layer1: acc1 = We·pe ; +R_i+U_j ; silu ; pack bf16 in regs (pk)
// Layer2: B-frag IS the lane's own pk words (k-convention chosen to match the C/D layout
//         of layer1 — k-permutation invariance makes any shared A/B convention valid);
//         A-frag (W2) read with the matching two-b64 pattern.
// s = W3·silu(acc2+b2); accd += s*mask*coord_diff; out = pos + 0.5*wave_reduce(accd)
__launch_bounds__(256, 2)
__global__ void posupd_main(const float* __restrict__ pe,
                            const float* __restrict__ pos,
                            const float* __restrict__ cd,
                            const float* __restrict__ pmask,
                            const float* __restrict__ b2,
                            const float* __restrict__ W3,
                            const float* __restrict__ R,
                            const float* __restrict__ U,
                            const uint4* __restrict__ Wcomb,  // We_b then W2_b, 64KB
                            float* __restrict__ out) {
  __shared__ uint4 wlds[4096];  // 64 KB: [0,32KB)=We, [32KB,64KB)=W2, XOR-swizzled rows
  const int tid = threadIdx.x;
  // ---- stage weights global->LDS with swizzle: byte ^= (row&7)<<4 ----
  // 16 uint4 per 128-bf16 row (256 B/row).
#pragma unroll
  for (int v = 0; v < 16; ++v) {
    int src = v * 256 + tid;            // uint4 index, coalesced
    uint4 val = Wcomb[src];
    int within = src & 2047;            // uint4 idx within one 32KB matrix
    int g = within >> 4;                // row (16 uint4 per row)
    int seg = within & 15;              // 16B segment within row
    int byteoff = (g << 8) + (seg << 4);
    byteoff ^= (g & 7) << 4;
    byteoff += (src >> 11) << 15;       // second matrix at +32KB
    *reinterpret_cast<uint4*>(reinterpret_cast<char*>(wlds) + byteoff) = val;
  }
  __syncthreads();

  const int lane = tid & 63;
  const int wv = tid >> 6;
  const int bb = blockIdx.y;
  const int i = blockIdx.x * 4 + wv;
  const int tok = lane & 31;   // MFMA column (token) / A-row within m-tile
  const int hh = lane >> 5;    // k-half select

  const char* we_lds = reinterpret_cast<const char*>(wlds);
  const char* w2_lds = we_lds + 32768;

  const float* peB = pe + ((size_t)bb * N_ + i) * N_ * H_;
  const float* Urow = U + (size_t)bb * N_ * H_;
  const float* Rrow = R + ((size_t)bb * N_ + i) * H_;
  const float* cdB = cd + ((size_t)bb * N_ + i) * N_ * 3;
  const float* pmB = pmask + ((size_t)bb * N_ + i) * N_;

  // Hoist wave-constant R (per-i row term) into registers: 16 x f32x4
  f32x4 rq[4][4];
#pragma unroll
  for (int mt = 0; mt < 4; ++mt)
#pragma unroll
    for (int u = 0; u < 4; ++u)
      rq[mt][u] = *reinterpret_cast<const f32x4*>(Rrow + mt * 32 + u * 8 + hh * 4);

  float accd0 = 0.f, accd1 = 0.f, accd2 = 0.f;

  for (int jt = 0; jt < 8; ++jt) {
    const int j0 = jt * 32;

    // ---- Phase A: load pair_emb rows (fp32) -> bf16 B-fragments ----
    // convention: slot (hh, e) holds k = 16*kt + 8*hh + e
    i32x4 bpe[8];
#pragma unroll
    for (int kt = 0; kt < 8; ++kt) {
      const float* p = peB + (size_t)(j0 + tok) * H_ + kt * 16 + hh * 8;
      f32x4 lo = *reinterpret_cast<const f32x4*>(p);
      f32x4 hi = *reinterpret_cast<const f32x4*>(p + 4);
      i32x4 f;
      f.x = (int)pack_bf16_pair(lo.x, lo.y);
      f.y = (int)pack_bf16_pair(lo.z, lo.w);
      f.z = (int)pack_bf16_pair(hi.x, hi.y);
      f.w = (int)pack_bf16_pair(hi.z, hi.w);
      bpe[kt] = f;
    }

    // ---- Phase B: layer-1 GEMM (A=We from LDS, same k-convention) ----
    f32x16 a1[4];
#pragma unroll
    for (int mt = 0; mt < 4; ++mt)
#pragma unroll
      for (int e = 0; e < 16; ++e) a1[mt][e] = 0.f;
#pragma unroll
    for (int kt = 0; kt < 8; ++kt) {
#pragma unroll
      for (int mt = 0; mt < 4; ++mt) {
        int g = mt * 32 + tok;
        int off = ((g << 8) + (kt << 5) + (hh << 4)) ^ ((g & 7) << 4);
        i32x4 afr = *reinterpret_cast<const i32x4*>(we_lds + off);
        a1[mt] = mfma_bf16(afr, bpe[kt], a1[mt]);
      }
    }

    // ---- Phase B2: + R_i + U_j, SiLU, pack to bf16 pairs ----
    // C/D layout (measured): acc1[mt][r] = h1_pre[g][tok], g = 32mt + (r&3) + 8(r>>2) + 4hh
    u32 pk[4][8];
#pragma unroll
    for (int mt = 0; mt < 4; ++mt) {
#pragma unroll
      for (int u = 0; u < 4; ++u) {
        int gq = mt * 32 + u * 8 + hh * 4;
        f32x4 uq = *reinterpret_cast<const f32x4*>(Urow + (size_t)(j0 + tok) * H_ + gq);
        f32x4 rr = rq[mt][u];
        float h0 = silu_f(a1[mt][u * 4 + 0] + uq.x + rr.x);
        float h1 = silu_f(a1[mt][u * 4 + 1] + uq.y + rr.y);
        float h2 = silu_f(a1[mt][u * 4 + 2] + uq.z + rr.z);
        float h3 = silu_f(a1[mt][u * 4 + 3] + uq.w + rr.w);
        pk[mt][2 * u] = pack_bf16_pair(h0, h1);
        pk[mt][2 * u + 1] = pack_bf16_pair(h2, h3);
      }
    }

    // ---- Phase C: layer-2 GEMM. B-frag = lane's own pk words.
    // Shared convention for this GEMM: slot (hh,e) -> k = 16*ktp + 8*(e>>2) + 4*hh + (e&3).
    // B-side: those are exactly channels this lane holds (from the C/D layout).
    // A-side: W2 row g, two b64 reads at inrow = 32*ktp + 8*hh and +16.
    f32x16 a2[4];
#pragma unroll
    for (int mt = 0; mt < 4; ++mt)
#pragma unroll
      for (int e = 0; e < 16; ++e) a2[mt][e] = 0.f;
#pragma unroll
    for (int ktp = 0; ktp < 8; ++ktp) {
      int T = ktp >> 1;
      int w0 = (ktp & 1) * 4;
      i32x4 bf;
      bf.x = (int)pk[T][w0 + 0];
      bf.y = (int)pk[T][w0 + 1];
      bf.z = (int)pk[T][w0 + 2];
      bf.w = (int)pk[T][w0 + 3];
#pragma unroll
      for (int mt = 0; mt < 4; ++mt) {
        int g = mt * 32 + tok;
        int swz = (g & 7) << 4;
        int base = (g << 8) + (ktp << 5) + (hh << 3);
        i32x2 alo = *reinterpret_cast<const i32x2*>(w2_lds + (base ^ swz));
        i32x2 ahi = *reinterpret_cast<const i32x2*>(w2_lds + ((base + 16) ^ swz));
        i32x4 afr;
        afr.x = alo.x; afr.y = alo.y; afr.z = ahi.x; afr.w = ahi.y;
        a2[mt] = mfma_bf16(afr, bf, a2[mt]);
      }
    }

    // ---- Phase D: +b2, SiLU, dot with W3 -> s[tok] ----
    float s_part = 0.f;
#pragma unroll
    for (int mt = 0; mt < 4; ++mt) {
#pragma unroll
      for (int u = 0; u < 4; ++u) {
        int gq = mt * 32 + u * 8 + hh * 4;
        f32x4 b2q = *reinterpret_cast<const f32x4*>(b2 + gq);
        f32x4 w3q = *reinterpret_cast<const f32x4*>(W3 + gq);
        s_part += silu_f(a2[mt][u * 4 + 0] + b2q.x) * w3q.x;
        s_part += silu_f(a2[mt][u * 4 + 1] + b2q.y) * w3q.y;
        s_part += silu_f(a2[mt][u * 4 + 2] + b2q.z) * w3q.z;
        s_part += silu_f(a2[mt][u * 4 + 3] + b2q.w) * w3q.w;
      }
    }
    float s = s_part + __shfl_xor(s_part, 32);

    // ---- Phase E: trans accumulation over j (both halves duplicate -> x0.5 later) ----
    int j = j0 + tok;
    float sm = s * pmB[j];
    const float* c = cdB + (size_t)j * 3;
    accd0 += sm * c[0];
    accd1 += sm * c[1];
    accd2 += sm * c[2];
  }

#pragma unroll
  for (int m = 1; m < 64; m <<= 1) {
    accd0 += __shfl_xor(accd0, m);
    accd1 += __shfl_xor(accd1, m);
    accd2 += __shfl_xor(accd2, m);
  }

  if (lane == 0) {
    const float* pp = pos + ((size_t)bb * N_ + i) * 3;
    float* oo = out + ((size_t)bb * N_ + i) * 3;
    oo[0] = pp[0] + 0.5f * accd0;
    oo[1] = pp[1] + 0.5f * accd1;
    oo[2] = pp[2] + 0.5f * accd2;
  }
}

extern "C" void kernel_launch(void* const* d_in, const int* in_sizes, int n_in,
                              void* d_out, int out_size, void* d_ws, size_t ws_size,
                              hipStream_t stream) {
  const float* x_emb     = (const float*)d_in[0];
  const float* pair_emb  = (const float*)d_in[1];
  const float* pos       = (const float*)d_in[2];
  const float* coord_diff= (const float*)d_in[3];
  // d_in[4] node_mask: unused by the reference computation
  const float* pair_mask = (const float*)d_in[5];
  const float* Wd        = (const float*)d_in[6];
  const float* bd        = (const float*)d_in[7];
  const float* W1        = (const float*)d_in[8];
  const float* b1        = (const float*)d_in[9];
  const float* W2        = (const float*)d_in[10];
  const float* b2        = (const float*)d_in[11];
  const float* W3        = (const float*)d_in[12];
  float* out = (float*)d_out;

  char* ws = (char*)d_ws;
  float* R   = (float*)ws;                         // 1 MB
  float* U   = (float*)(ws + (1 << 20));           // 1 MB
  u16*   WeB = (u16*)(ws + (2 << 20));             // 32 KB
  u16*   W2B = (u16*)(ws + (2 << 20) + 32768);     // 32 KB

  hipLaunchKernelGGL(prep_ru_kernel, dim3((B_ * N_) / 16), dim3(128), 0, stream,
                     x_emb, W1, b1, bd, R, U);
  hipLaunchKernelGGL(prep_w_kernel, dim3(64), dim3(256), 0, stream,
                     W1, Wd, W2, WeB, W2B);
  hipLaunchKernelGGL(posupd_main, dim3(N_ / 4, B_), dim3(256), 0, stream,
                     pair_emb, pos, coord_diff, pair_mask, b2, W3,
                     R, U, (const uint4*)(ws + (2 << 20)), out);
}

// Round 3
// 462.435 us; speedup vs baseline: 1.6248x; 1.6248x over previous
//
#include <hip/hip_runtime.h>
#include <cstdint>
#include <cstddef>

// Problem constants (B=8, N=256, H=128, IN_DIM=259)
#define B_ 8
#define N_ 256
#define H_ 128

typedef float f32x4 __attribute__((ext_vector_type(4)));
typedef int i32x4 __attribute__((ext_vector_type(4)));
typedef int i32x2 __attribute__((ext_vector_type(2)));
typedef __bf16 bf16x8 __attribute__((ext_vector_type(8)));
typedef unsigned int u32;
typedef unsigned short u16;

// ---------- helpers ----------
__device__ __forceinline__ u32 pack_bf16_pair(float lo, float hi) {
  u16 a = __builtin_bit_cast(u16, (__bf16)lo);
  u16 b = __builtin_bit_cast(u16, (__bf16)hi);
  return (u32)a | ((u32)b << 16);
}

__device__ __forceinline__ float silu_f(float x) {
  return x * __builtin_amdgcn_rcpf(1.0f + __expf(-x));
}

__device__ __forceinline__ f32x4 mfma16(i32x4 a, i32x4 b, f32x4 c) {
  return __builtin_amdgcn_mfma_f32_16x16x32_bf16(
      __builtin_bit_cast(bf16x8, a), __builtin_bit_cast(bf16x8, b), c, 0, 0, 0);
}

// ---------- precompute: R[b,n,g] = x[b,n]·W1[:, :128]ᵀ (linear layout);
// U[b,n,g] = x[b,n]·W1[:,128:256]ᵀ + b1 + W1[:,256:259]·bd, stored with in-row
// swizzle elem' = g ^ ((n&7)<<2) so the main kernel can stage it linearly into
// LDS and read bank-conflict-free f32x4s with the matching XOR. ----------
__global__ void prep_ru_kernel(const float* __restrict__ x_emb,
                               const float* __restrict__ W1,
                               const float* __restrict__ b1,
                               const float* __restrict__ bd,
                               float* __restrict__ R,
                               float* __restrict__ U) {
  __shared__ float xs[16][H_];
  const int t = threadIdx.x;          // 0..127 (= output channel g)
  const int row0 = blockIdx.x * 16;   // rows over flattened (b*N+n)
#pragma unroll
  for (int r = 0; r < 16; ++r)
    xs[r][t] = x_emb[(size_t)(row0 + r) * H_ + t];
  __syncthreads();

  const float* w1g = W1 + (size_t)t * 259;
  float accR[16], accU[16];
#pragma unroll
  for (int r = 0; r < 16; ++r) { accR[r] = 0.f; accU[r] = 0.f; }
  for (int h = 0; h < H_; ++h) {
    float wa = w1g[h];
    float wb = w1g[128 + h];
#pragma unroll
    for (int r = 0; r < 16; ++r) {
      accR[r] += xs[r][h] * wa;
      accU[r] += xs[r][h] * wb;
    }
  }
  float bias = b1[t] + bd[0] * w1g[256] + bd[1] * w1g[257] + bd[2] * w1g[258];
#pragma unroll
  for (int r = 0; r < 16; ++r) {
    int n = (row0 + r) & (N_ - 1);
    R[(size_t)(row0 + r) * H_ + t] = accR[r];
    U[(size_t)(row0 + r) * H_ + (t ^ ((n & 7) << 2))] = accU[r] + bias;
  }
}

// ---------- precompute: We = W1[:,256:259]·Wd folded (bf16), W2 (bf16),
// both stored PRE-SWIZZLED so main's LDS staging is a linear copy:
//   We: 16B granule  seg' = (h>>3) ^ (g&7)
//   W2:  8B granule  seg' = (h>>2) ^ (g&7)
__global__ void prep_w_kernel(const float* __restrict__ W1,
                              const float* __restrict__ Wd,
                              const float* __restrict__ W2,
                              u16* __restrict__ We_b,
                              u16* __restrict__ W2_b) {
  const int idx = blockIdx.x * 256 + threadIdx.x;  // 0..16383
  const int g = idx >> 7, h = idx & 127;
  const float* w1g = W1 + (size_t)g * 259 + 256;
  float we = w1g[0] * Wd[h] + w1g[1] * Wd[128 + h] + w1g[2] * Wd[256 + h];
  int se = (h >> 3) ^ (g & 7);                       // 0..15
  We_b[g * 128 + (se << 3) + (h & 7)] = __builtin_bit_cast(u16, (__bf16)we);
  int s2 = (h >> 2) ^ (g & 7);                       // 0..31
  W2_b[g * 128 + (s2 << 2) + (h & 3)] = __builtin_bit_cast(u16, (__bf16)W2[idx]);
}

// ---------- main fused kernel ----------
// Block = 1024 thr = 16 waves = 4 i × 4 j-subtiles; wave = one (b,i, 16 j's).
// 16x16x32 bf16 MFMA: M=channel(128: 8 m-tiles of 16), N=16 tokens, K=128 (4 k-tiles).
// lane: tok = lane&15 (token/row), kg = lane>>4 (k-quarter). Shared injective
// k-slot convention on A and B sides makes exact HW k-wiring irrelevant
// (k-permutation invariance, verified on HW in round 2 for 32x32).
// LDS 96KB: [0,32K) We (swz (g&7)<<4), [32K,64K) W2 (swz (g&7)<<3),
//           [64K,96K) U tile 64 rows (swz (j&7)<<4). All staged linearly.
__launch_bounds__(1024, 4)
__global__ void posupd_main(const float* __restrict__ pe,
                            const float* __restrict__ cd,
                            const float* __restrict__ pmask,
                            const float* __restrict__ b2,
                            const float* __restrict__ W3,
                            const float* __restrict__ R,
                            const float* __restrict__ U,
                            const uint4* __restrict__ Wcomb,  // We_b | W2_b, 64KB
                            float* __restrict__ partial) {
  __shared__ uint4 ldsv[6144];  // 96 KB
  char* lds = (char*)ldsv;
  const int tid = threadIdx.x;
  const int lane = tid & 63, wv = tid >> 6;     // wv 0..15
  const int bid = blockIdx.x;
  const int b = bid >> 8;
  const int rem = bid & 255;
  const int ig = rem >> 2, jg = rem & 3;        // i-group (of 4), j-group (of 64)

  // ---- stage 96 KB = 96 chunks x 1KB, linear copy (sources pre-swizzled) ----
  const uint4* Usrc = (const uint4*)(U + ((size_t)b * N_ + jg * 64) * H_);
#pragma unroll
  for (int c = 0; c < 6; ++c) {
    int k = wv * 6 + c;                                   // 0..95
    const uint4* src = (k < 64) ? (Wcomb + (k << 6) + lane)
                                : (Usrc + ((k - 64) << 6) + lane);
    *reinterpret_cast<uint4*>(lds + (k << 10) + (lane << 4)) = *src;
  }
  __syncthreads();

  const int tok = lane & 15, kg = lane >> 4;
  const int iw = wv & 3, jtw = wv >> 2;
  const int i = ig * 4 + iw;
  const int jl = jtw * 16 + tok;                // local j within 64-row tile
  const size_t bi = (size_t)b * N_ + i;
  const int jgl = jg * 64 + jl;                 // global j

  // ---- Phase A: pe row -> bf16 B-fragments (slot(kg,e) = 8kg+e per k-tile) ----
  const float* perow = pe + (bi * N_ + jgl) * H_;
  i32x4 bpe[4];
#pragma unroll
  for (int kt = 0; kt < 4; ++kt) {
    const float* p = perow + kt * 32 + kg * 8;
    f32x4 lo = *reinterpret_cast<const f32x4*>(p);
    f32x4 hi = *reinterpret_cast<const f32x4*>(p + 4);
    i32x4 f;
    f.x = (int)pack_bf16_pair(lo.x, lo.y);
    f.y = (int)pack_bf16_pair(lo.z, lo.w);
    f.z = (int)pack_bf16_pair(hi.x, hi.y);
    f.w = (int)pack_bf16_pair(hi.z, hi.w);
    bpe[kt] = f;
  }

  // ---- Phase B: layer-1 GEMM, A=We from LDS (b128, swizzled) ----
  f32x4 a1[8];
#pragma unroll
  for (int mt = 0; mt < 8; ++mt) { a1[mt].x = a1[mt].y = a1[mt].z = a1[mt].w = 0.f; }
#pragma unroll
  for (int kt = 0; kt < 4; ++kt) {
#pragma unroll
    for (int mt = 0; mt < 8; ++mt) {
      int g = mt * 16 + tok;
      int off = (g << 8) + (((kt << 6) + (kg << 4)) ^ ((g & 7) << 4));
      i32x4 afr = *reinterpret_cast<const i32x4*>(lds + off);
      a1[mt] = mfma16(afr, bpe[kt], a1[mt]);
    }
  }

  // ---- Phase B2: + R_i + U_j (from LDS tile), SiLU, pack ----
  // C/D layout: a1[mt][r] = pre[g = 16mt + 4kg + r][tok]
  const float* Rrow = R + bi * H_;
  u32 pk0[8], pk1[8];
#pragma unroll
  for (int mt = 0; mt < 8; ++mt) {
    int ch = mt * 16 + kg * 4;
    f32x4 rr = *reinterpret_cast<const f32x4*>(Rrow + ch);
    int ub = 65536 + (jl << 9) + ((ch << 2) ^ ((jl & 7) << 4));
    f32x4 uu = *reinterpret_cast<const f32x4*>(lds + ub);
    float h0 = silu_f(a1[mt].x + rr.x + uu.x);
    float h1 = silu_f(a1[mt].y + rr.y + uu.y);
    float h2 = silu_f(a1[mt].z + rr.z + uu.z);
    float h3 = silu_f(a1[mt].w + rr.w + uu.w);
    pk0[mt] = pack_bf16_pair(h0, h1);
    pk1[mt] = pack_bf16_pair(h2, h3);
  }

  // ---- Phase C: layer-2 GEMM. B-frag = lane's own pk words.
  // slot2(kg, e=m*4+r) = 16m + 4kg + r within k-tile kt2 (channels 32*kt2+...).
  // A-side (W2): two b64 reads per (kt2, mt), swz (g&7)<<3.
  f32x4 a2[8];
#pragma unroll
  for (int mt = 0; mt < 8; ++mt) { a2[mt].x = a2[mt].y = a2[mt].z = a2[mt].w = 0.f; }
#pragma unroll
  for (int kt2 = 0; kt2 < 4; ++kt2) {
    i32x4 bfr;
    bfr.x = (int)pk0[2 * kt2];
    bfr.y = (int)pk1[2 * kt2];
    bfr.z = (int)pk0[2 * kt2 + 1];
    bfr.w = (int)pk1[2 * kt2 + 1];
#pragma unroll
    for (int mt = 0; mt < 8; ++mt) {
      int g = mt * 16 + tok;
      int base = 32768 + (g << 8);
      int sw = (g & 7) << 3;
      i32x2 alo = *reinterpret_cast<const i32x2*>(lds + base + (((kt2 << 6) + (kg << 3)) ^ sw));
      i32x2 ahi = *reinterpret_cast<const i32x2*>(lds + base + (((kt2 << 6) + 32 + (kg << 3)) ^ sw));
      i32x4 afr;
      afr.x = alo.x; afr.y = alo.y; afr.z = ahi.x; afr.w = ahi.y;
      a2[mt] = mfma16(afr, bfr, a2[mt]);
    }
  }

  // ---- Phase D: +b2, SiLU, partial dot with W3 (lane holds 32 of 128 ch) ----
  float sp = 0.f;
#pragma unroll
  for (int mt = 0; mt < 8; ++mt) {
    int ch = mt * 16 + kg * 4;
    f32x4 bb = *reinterpret_cast<const f32x4*>(b2 + ch);
    f32x4 ww = *reinterpret_cast<const f32x4*>(W3 + ch);
    sp += silu_f(a2[mt].x + bb.x) * ww.x;
    sp += silu_f(a2[mt].y + bb.y) * ww.y;
    sp += silu_f(a2[mt].z + bb.z) * ww.z;
    sp += silu_f(a2[mt].w + bb.w) * ww.w;
  }

  // ---- Phase E: trans partials; wave-reduce sums over (tok, kg) exactly ----
  size_t pidx = bi * N_ + jgl;
  float sm = sp * pmask[pidx];
  const float* c3 = cd + pidx * 3;
  float aX = sm * c3[0], aY = sm * c3[1], aZ = sm * c3[2];
#pragma unroll
  for (int m = 1; m < 64; m <<= 1) {
    aX += __shfl_xor(aX, m);
    aY += __shfl_xor(aY, m);
    aZ += __shfl_xor(aZ, m);
  }
  if (lane == 0) {
    float* pp = partial + ((bi << 4) + (jg << 2) + jtw) * 3;
    pp[0] = aX; pp[1] = aY; pp[2] = aZ;
  }
}

// ---------- deterministic j-partial reduction: out = pos + sum(16 partials) ----------
__global__ void reduce_out(const float* __restrict__ partial,
                           const float* __restrict__ pos,
                           float* __restrict__ out) {
  int t = blockIdx.x * 256 + threadIdx.x;  // 0..2047 = (b,i)
  if (t >= B_ * N_) return;
  const float* p = partial + (size_t)t * 48;
  float s0 = 0.f, s1 = 0.f, s2 = 0.f;
#pragma unroll
  for (int q = 0; q < 16; ++q) {
    s0 += p[q * 3 + 0];
    s1 += p[q * 3 + 1];
    s2 += p[q * 3 + 2];
  }
  out[t * 3 + 0] = pos[t * 3 + 0] + s0;
  out[t * 3 + 1] = pos[t * 3 + 1] + s1;
  out[t * 3 + 2] = pos[t * 3 + 2] + s2;
}

extern "C" void kernel_launch(void* const* d_in, const int* in_sizes, int n_in,
                              void* d_out, int out_size, void* d_ws, size_t ws_size,
                              hipStream_t stream) {
  const float* x_emb      = (const float*)d_in[0];
  const float* pair_emb   = (const float*)d_in[1];
  const float* pos        = (const float*)d_in[2];
  const float* coord_diff = (const float*)d_in[3];
  // d_in[4] node_mask: unused by the reference computation
  const float* pair_mask  = (const float*)d_in[5];
  const float* Wd         = (const float*)d_in[6];
  const float* bd         = (const float*)d_in[7];
  const float* W1         = (const float*)d_in[8];
  const float* b1         = (const float*)d_in[9];
  const float* W2         = (const float*)d_in[10];
  const float* b2         = (const float*)d_in[11];
  const float* W3         = (const float*)d_in[12];
  float* out = (float*)d_out;

  char* ws = (char*)d_ws;
  float* R       = (float*)ws;                               // 1 MB
  float* U       = (float*)(ws + (1 << 20));                 // 1 MB (swizzled rows)
  u16*   WeB     = (u16*)(ws + (2 << 20));                   // 32 KB (pre-swizzled)
  u16*   W2B     = (u16*)(ws + (2 << 20) + 32768);           // 32 KB (pre-swizzled)
  float* partial = (float*)(ws + (2 << 20) + 65536);         // 384 KB

  hipLaunchKernelGGL(prep_ru_kernel, dim3((B_ * N_) / 16), dim3(128), 0, stream,
                     x_emb, W1, b1, bd, R, U);
  hipLaunchKernelGGL(prep_w_kernel, dim3(64), dim3(256), 0, stream,
                     W1, Wd, W2, WeB, W2B);
  hipLaunchKernelGGL(posupd_main, dim3(2048), dim3(1024), 0, stream,
                     pair_emb, coord_diff, pair_mask, b2, W3,
                     R, U, (const uint4*)(ws + (2 << 20)), partial);
  hipLaunchKernelGGL(reduce_out, dim3(8), dim3(256), 0, stream,
                     partial, pos, out);
}